// Round 13
// baseline (289.414 us; speedup 1.0000x reference)
//
#include <hip/hip_runtime.h>
#include <hip/hip_bf16.h>

// Problem constants
#define NB    8
#define SQN   2048
#define SKN   4096
#define DDIM  512
#define DVDIM 256
#define NROWS (NB*SQN)      // 16384
#define NS    4             // SK splits (R13: 2 -> 4 for 2x wave count / TLP)
#define NJ    ((SKN/64)/NS) // 16 j-iterations per split (64 keys each)

typedef __attribute__((ext_vector_type(8)))  short bf16x8;   // 8 bf16 = 4 VGPRs (MFMA A/B frag)
typedef __attribute__((ext_vector_type(4)))  short bf16x4;
typedef __attribute__((ext_vector_type(4)))  float f32x4;    // 16x16 MFMA C/D frag
typedef __attribute__((ext_vector_type(16))) float f32x16;   // 32x32 MFMA C/D frag

// fp32 -> bf16 round-to-nearest-even, bit pattern as short
__device__ __forceinline__ short f2bf(float f) {
    unsigned u = __float_as_uint(f);
    return (short)((u + 0x7FFFu + ((u >> 16) & 1u)) >> 16);
}

// LDS-only barrier: vm loads (K/V register prefetches) stay in flight.
// sched_barrier fences per rule #18 (no hoisting across the asm wait).
#define BAR_LGKM() do {                                                       \
    asm volatile("s_waitcnt lgkmcnt(0)" ::: "memory");                        \
    __builtin_amdgcn_sched_barrier(0);                                        \
    __builtin_amdgcn_s_barrier();                                             \
    __builtin_amdgcn_sched_barrier(0);                                        \
} while (0)

// ---------------------------------------------------------------------------
// Fused projection GEMMs, one launch. grid = (64, 8, 2).  (unchanged from R8)
// Epilogues write K/V PRE-PACKED in fragment-lane order (16B units;
// lane = hi*32 + l31):
//  K: tile ((J*4+c)*8+tp)*2+kh holds K[J*64+kh*32+l31][c*128+tp*16+hi*8+..7]
//  V: tile (J*8+wv*4+n2)*4+g   holds V^T[wv*128+n2*32+l31][J*64+g*16+hi*8+..7]
// ---------------------------------------------------------------------------
__global__ __launch_bounds__(256, 2) void proj_gemms(
    const float* __restrict__ Y, const float* __restrict__ Z,
    const float* __restrict__ Wk, const float* __restrict__ Wv,
    unsigned short* __restrict__ keyb, unsigned short* __restrict__ vtb)
{
    __shared__ short sA[64*128];   // 16 KB
    __shared__ short sB[64*128];   // 16 KB
    const float *A, *Bm;
    unsigned short* C;
    int m0, n0;
    const bool kpath = (blockIdx.z == 0);
    if (kpath) {
        A = Y; Bm = Wk; C = keyb;
        m0 = blockIdx.x * 64; n0 = blockIdx.y * 64;
    } else {
        int lin = blockIdx.x * 8 + blockIdx.y;
        if (lin >= 256) return;                 // value GEMM needs 256 tiles
        A = Wv; Bm = Z; C = vtb;
        m0 = (lin >> 6) * 64; n0 = (lin & 63) * 64;
    }
    const int tid  = threadIdx.x;
    const int wave = tid >> 6;
    const int lane = tid & 63;
    const int quad = lane >> 4;
    const int l15  = lane & 15;

    f32x4 acc[4];
    #pragma unroll
    for (int n = 0; n < 4; ++n) { acc[n][0]=0.f; acc[n][1]=0.f; acc[n][2]=0.f; acc[n][3]=0.f; }

    float4 ra[8], rb[8];
    #pragma unroll
    for (int it = 0; it < 8; ++it) {            // prefetch kc=0
        int f = it*1024 + tid*4, row = f >> 7, col = f & 127;
        ra[it] = *(const float4*)(A  + (size_t)(m0+row)*DDIM + col);
        rb[it] = *(const float4*)(Bm + (size_t)(n0+row)*DDIM + col);
    }

    for (int kc = 0; kc < DDIM; kc += 128) {
        __syncthreads();                        // LDS free (prev MFMA done)
        #pragma unroll
        for (int it = 0; it < 8; ++it) {
            int f = it*1024 + tid*4;
            bf16x4 a4; a4[0]=f2bf(ra[it].x); a4[1]=f2bf(ra[it].y); a4[2]=f2bf(ra[it].z); a4[3]=f2bf(ra[it].w);
            *(bf16x4*)(sA + f) = a4;
            bf16x4 b4; b4[0]=f2bf(rb[it].x); b4[1]=f2bf(rb[it].y); b4[2]=f2bf(rb[it].z); b4[3]=f2bf(rb[it].w);
            *(bf16x4*)(sB + f) = b4;
        }
        __syncthreads();                        // staged visible
        if (kc + 128 < DDIM) {                  // prefetch kc+1 (in flight under MFMA)
            #pragma unroll
            for (int it = 0; it < 8; ++it) {
                int f = it*1024 + tid*4, row = f >> 7, col = f & 127;
                ra[it] = *(const float4*)(A  + (size_t)(m0+row)*DDIM + kc + 128 + col);
                rb[it] = *(const float4*)(Bm + (size_t)(n0+row)*DDIM + kc + 128 + col);
            }
        }
        #pragma unroll
        for (int t = 0; t < 4; ++t) {
            bf16x8 af = *(const bf16x8*)(sA + (wave*16 + l15)*128 + t*32 + quad*8);
            #pragma unroll
            for (int n = 0; n < 4; ++n) {
                bf16x8 bfr = *(const bf16x8*)(sB + (n*16 + l15)*128 + t*32 + quad*8);
                acc[n] = __builtin_amdgcn_mfma_f32_16x16x32_bf16(af, bfr, acc[n], 0, 0, 0);
            }
        }
    }
    // packed epilogue
    #pragma unroll
    for (int n = 0; n < 4; ++n)
        #pragma unroll
        for (int r = 0; r < 4; ++r) {
            int m  = m0 + wave*16 + quad*4 + r;
            int nn = n0 + n*16 + l15;
            unsigned short v = (unsigned short)f2bf(acc[n][r]);
            size_t off;
            if (kpath) {        // s=m (key row), d=nn
                int J = m >> 6, kh = (m >> 5) & 1, ls = m & 31;
                int c = nn >> 7, tp = (nn >> 4) & 7, hd = (nn >> 3) & 1, d7 = nn & 7;
                off = (size_t)(((J*4 + c)*8 + tp)*2 + kh)*512 + (hd*32 + ls)*8 + d7;
            } else {            // dv=m, key=nn
                int J = nn >> 6, g = (nn >> 4) & 3, hk = (nn >> 3) & 1, k7 = nn & 7;
                int wv = m >> 7, n2 = (m >> 5) & 3, lv = m & 31;
                off = (size_t)((J*8 + wv*4 + n2)*4 + g)*512 + (hk*32 + lv)*8 + k7;
            }
            C[off] = v;
        }
}

// ---------------------------------------------------------------------------
// Fused attention, R13 = R8 body (152 us, VGPR=100, proven) at NS=4.
// R9/R12 post-mortem: intra-wave fixes (2x work, j-pipeline) were neutral;
// every pipe sits at ~25% with 8 waves/CU (grid-capped occupancy 20%) ->
// LATENCY-bound from insufficient TLP. Fix: 4 SK-splits -> 2048 blocks =
// 4096 waves (up to 16/CU, reg-limited ~11-12 = ~3/SIMD). Work/wave halves
// (NJ=16), totals unchanged. Per-XCD K+V drops to 1.5 MB (2 XCDs/split).
// Body unchanged from R8: packed coalesced K/V global->reg (kf ring depth-2,
// vf 2 banks), Q in LDS, wk-pair key-split with 2 lgkm-only exchanges/j,
// T13 defer-max log2 softmax, cvt_pk+permlane P->A-frags.
// grid = 2048, block = 128 (one wk pair).
// ---------------------------------------------------------------------------
__global__ __launch_bounds__(128, 2) void attn_fused(
    const float* __restrict__ X,            // [16384][512] fp32
    const unsigned short* __restrict__ Kb,  // key bf16, PACKED (4 MB)
    const unsigned short* __restrict__ Vt,  // V^T bf16, PACKED (2 MB)
    float* __restrict__ Opart,              // [NS][16384][256]
    float* __restrict__ Mpart,              // [NS][16384] (log2 domain)
    float* __restrict__ Lpart)              // [NS][16384]
{
    // 0     : sQ 32KB [t2=32][lane]x16B  (Q B-frag tile t2: elem e =
    //         X[q0+l31][t2*16 + hi*8 + e]*scale)
    // 32768 : sPex 4KB [wk*2+ks][lane]x16B P A-frags
    // 36864 : sSt 512B [wk*2+slot][32] floats
    __shared__ __align__(16) char smem[37376];
    char* sQ   = smem;
    char* sPex = smem + 32768;
    float* sSt = (float*)(smem + 36864);

    const int tid  = threadIdx.x;
    const int wk   = tid >> 6;      // 0..1: key-half for QK / dv-half for PV
    const int lane = tid & 63;
    const int l31  = lane & 31;
    const int hi   = lane >> 5;

    // XCD-split swizzle: bid&7 = XCD; 2 XCDs per split (split = xcd>>1)
    // -> per-XCD K+V working set 1.5 MB, L2-resident.
    const int bid   = blockIdx.x;          // 0..2047
    const int xcd   = bid & 7;
    const int slot  = bid >> 3;            // 0..255
    const int split = xcd >> 1;            // 0..3
    const int q0    = ((xcd & 1)*256 + slot) * 32;
    // 1/sqrt(512) * log2(e): softmax runs in log2 domain (exp2)
    const float scale = 0.04419417382415922f * 1.4426950408889634f;

    // ---- prologue: stage this block's 32 Q frag-tiles to LDS (wk splits) ----
    {
        const float* xrow = X + (size_t)(q0 + l31)*DDIM + hi*8;
        #pragma unroll
        for (int i = 0; i < 16; ++i) {
            const int t2 = wk*16 + i;
            float4 a = *(const float4*)(xrow + t2*16);
            float4 b = *(const float4*)(xrow + t2*16 + 4);
            bf16x8 q;
            q[0]=f2bf(a.x*scale); q[1]=f2bf(a.y*scale); q[2]=f2bf(a.z*scale); q[3]=f2bf(a.w*scale);
            q[4]=f2bf(b.x*scale); q[5]=f2bf(b.y*scale); q[6]=f2bf(b.z*scale); q[7]=f2bf(b.w*scale);
            *(bf16x8*)(sQ + t2*1024 + lane*16) = q;
        }
    }

    // O acc: D[row=q][col=dv], wave's dv-half = wk*128 + n*32 + l31.
    f32x16 o[4];
    #pragma unroll
    for (int n = 0; n < 4; ++n)
        #pragma unroll
        for (int r = 0; r < 16; ++r) o[n][r] = 0.f;
    float m_r = -1e30f, l_r = 0.f;       // shared across wk pair

    // packed base pointers (this wave's key-half / dv-half, lane folded in)
    const int Jg0 = split * NJ;
    const char* kp = (const char*)Kb + (size_t)Jg0*65536 + wk*1024 + lane*16;
    const char* vp = (const char*)Vt + (size_t)Jg0*32768 + wk*16384 + lane*16;
    // K frag (h,t): kp + (h>>1)*16384 + (((h&1)*4+t)*2)*1024
    // V frag (n,g): vp + n*4096 + g*1024
    #define KOFF(h_, t_) ((size_t)((h_)>>1)*16384 + (size_t)((((h_)&1)*4 + (t_))*2)*1024)

    bf16x8 kf[3][4];                    // depth-2 ring (48 VGPR)
    bf16x8 vf[2][4];                    // PV double buffer (32 VGPR)

    BAR_LGKM();                         // Q visible to the pair

    // prologue loads: j=0 half-chunks 0,1 -> buf0, buf1
    #pragma unroll
    for (int t = 0; t < 4; ++t) kf[0][t] = *(const bf16x8*)(kp + KOFF(0, t));
    #pragma unroll
    for (int t = 0; t < 4; ++t) kf[1][t] = *(const bf16x8*)(kp + KOFF(1, t));

    const char* qb = sQ + lane*16;

    for (int j = 0; j < NJ; ++j) {
        f32x16 s;                       // P^T acc: D[row=key][col=q]
        #pragma unroll
        for (int r = 0; r < 16; ++r) s[r] = 0.f;

        // ---- QK: 8 phases; issue kf(h+2) at phase h (depth-2); V g0/g1
        //      issued at phases 6/7 (drain under softmax) ----
        #pragma unroll
        for (int h = 0; h < 8; ++h) {
            if (h < 6) {
                #pragma unroll
                for (int t = 0; t < 4; ++t)
                    kf[(h + 2) % 3][t] = *(const bf16x8*)(kp + KOFF(h + 2, t));
            } else {
                const int g = h - 6;    // V windows g=0,1
                #pragma unroll
                for (int n = 0; n < 4; ++n)
                    vf[g][n] = *(const bf16x8*)(vp + n*4096 + g*1024);
            }
            __builtin_amdgcn_s_setprio(1);
            #pragma unroll
            for (int t = 0; t < 4; ++t) {
                bf16x8 qv = *(const bf16x8*)(qb + (h*4 + t)*1024);
                s = __builtin_amdgcn_mfma_f32_32x32x16_bf16(
                        kf[h % 3][t], qv, s, 0, 0, 0);
            }
            __builtin_amdgcn_s_setprio(0);
        }

        // ---- softmax (log2 domain), in-lane; joint max across wk pair ----
        float tmax = fmaxf(fmaxf(fmaxf(s[0],s[1]),fmaxf(s[2],s[3])),
                           fmaxf(fmaxf(s[4],s[5]),fmaxf(s[6],s[7])));
        tmax = fmaxf(tmax, fmaxf(fmaxf(fmaxf(s[8],s[9]),fmaxf(s[10],s[11])),
                                 fmaxf(fmaxf(s[12],s[13]),fmaxf(s[14],s[15]))));
        tmax = fmaxf(tmax, __shfl_xor(tmax, 32));
        if (lane < 32) sSt[(wk*2 + 0)*32 + lane] = tmax;
        BAR_LGKM();                                             // exchange 1
        float tmax_o = sSt[((wk^1)*2 + 0)*32 + l31];
        const float tj   = fmaxf(tmax, tmax_o);
        // T13 defer-max: only move the reference when it grew by >8 (p <= 2^8)
        const bool  upd  = tj > m_r + 8.0f;
        const float mn   = upd ? tj : m_r;
        float tsum = 0.f;
        #pragma unroll
        for (int r = 0; r < 16; ++r) { float pv = exp2f(s[r] - mn); s[r] = pv; tsum += pv; }
        tsum += __shfl_xor(tsum, 32);

        // P -> PV A-frags in-register (cvt_pk + permlane32_swap, proven R1-R12)
        bf16x8 pf[2];
        #pragma unroll
        for (int ks = 0; ks < 2; ++ks) {
            int wA, wB, wC, wD;
            asm("v_cvt_pk_bf16_f32 %0, %1, %2" : "=v"(wA) : "v"(s[8*ks+0]), "v"(s[8*ks+1]));
            asm("v_cvt_pk_bf16_f32 %0, %1, %2" : "=v"(wB) : "v"(s[8*ks+2]), "v"(s[8*ks+3]));
            asm("v_cvt_pk_bf16_f32 %0, %1, %2" : "=v"(wC) : "v"(s[8*ks+4]), "v"(s[8*ks+5]));
            asm("v_cvt_pk_bf16_f32 %0, %1, %2" : "=v"(wD) : "v"(s[8*ks+6]), "v"(s[8*ks+7]));
            asm("v_permlane32_swap_b32 %0, %1" : "+v"(wA), "+v"(wC));
            asm("v_permlane32_swap_b32 %0, %1" : "+v"(wB), "+v"(wD));
            union { int w[4]; bf16x8 v; } u;
            u.w[0] = wA; u.w[1] = wB; u.w[2] = wC; u.w[3] = wD;
            pf[ks] = u.v;
        }
        *(bf16x8*)(sPex + (wk*2 + 0)*1024 + lane*16) = pf[0];
        *(bf16x8*)(sPex + (wk*2 + 1)*1024 + lane*16) = pf[1];
        if (lane < 32) sSt[(wk*2 + 1)*32 + lane] = tsum;

        // issue next-j K half-chunks 0,1 (in flight across exchange+PV)
        if (j + 1 < NJ) {
            kp += 65536;
            #pragma unroll
            for (int t = 0; t < 4; ++t) kf[0][t] = *(const bf16x8*)(kp + KOFF(0, t));
            #pragma unroll
            for (int t = 0; t < 4; ++t) kf[1][t] = *(const bf16x8*)(kp + KOFF(1, t));
        }
        BAR_LGKM();                                             // exchange 2
        float tsum_o = sSt[((wk^1)*2 + 1)*32 + l31];
        float alpha  = upd ? exp2f(m_r - mn) : 1.0f;
        l_r = l_r*alpha + (tsum + tsum_o);
        m_r = mn;
        if (__any(upd)) {               // rescale O (alpha indexed by q-row)
            #pragma unroll
            for (int r = 0; r < 16; ++r) {
                int row = (r&3) + 8*(r>>2) + 4*hi;
                float ar = __shfl(alpha, row);
                #pragma unroll
                for (int n = 0; n < 4; ++n) o[n][r] *= ar;
            }
        }

        // ---- PV: O[dv-half wk] += P(all 64 keys) * V^T; issue V(g+2)
        //      after MFMAs of g (buffer free, drains under next phase) ----
        const char* pb = sPex + lane*16;
        #pragma unroll
        for (int g = 0; g < 4; ++g) {
            bf16x8 pa = ((g >> 1) == wk) ? pf[g & 1]
                        : *(const bf16x8*)(pb + g*1024);
            __builtin_amdgcn_s_setprio(1);
            #pragma unroll
            for (int n = 0; n < 4; ++n)
                o[n] = __builtin_amdgcn_mfma_f32_32x32x16_bf16(
                        pa, vf[g & 1][n], o[n], 0, 0, 0);
            __builtin_amdgcn_s_setprio(0);
            if (g < 2) {
                #pragma unroll
                for (int n = 0; n < 4; ++n)
                    vf[g][n] = *(const bf16x8*)(vp + n*4096 + (g + 2)*1024);
            }
        }
        vp += 32768;
    }
    #undef KOFF

    // ---- epilogue: shared (m,l) across wk; disjoint dv halves -> no merge ----
    const size_t base = (size_t)split * NROWS;
    if (wk == 0 && lane < 32) {
        Mpart[base + q0 + lane] = m_r;      // log2 domain
        Lpart[base + q0 + lane] = l_r;
    }
    #pragma unroll
    for (int r = 0; r < 16; ++r) {
        int row = (r&3) + 8*(r>>2) + 4*hi;
        float* orow = Opart + (base + q0 + row) * (size_t)DVDIM + wk*128;
        #pragma unroll
        for (int n = 0; n < 4; ++n)
            orow[n*32 + l31] = o[n][r];
    }
}

// ---------------------------------------------------------------------------
// Combine NS split partials: out = sum_s(Os*ws) / sum_s(ls*ws), ws=2^(ms-M)
// (Mpart is log2-domain). grid = NROWS/4, block = 256. Coalesced.
// ---------------------------------------------------------------------------
__global__ void combine_splits(
    const float* __restrict__ Opart, const float* __restrict__ Mpart,
    const float* __restrict__ Lpart, float* __restrict__ out)
{
    const int row = blockIdx.x * 4 + (threadIdx.x >> 6);
    const int dv4 = (threadIdx.x & 63) * 4;
    float M = -1e30f;
    #pragma unroll
    for (int s = 0; s < NS; ++s) M = fmaxf(M, Mpart[(size_t)s*NROWS + row]);
    float denom = 0.f;
    float4 acc = make_float4(0.f, 0.f, 0.f, 0.f);
    #pragma unroll
    for (int s = 0; s < NS; ++s) {
        float w = exp2f(Mpart[(size_t)s*NROWS + row] - M);
        denom += Lpart[(size_t)s*NROWS + row] * w;
        float4 ov = *(const float4*)(Opart + ((size_t)s*NROWS + row)*DVDIM + dv4);
        acc.x += ov.x*w; acc.y += ov.y*w; acc.z += ov.z*w; acc.w += ov.w*w;
    }
    float inv = 1.0f / denom;
    *(float4*)(out + (size_t)row*DVDIM + dv4)
        = make_float4(acc.x*inv, acc.y*inv, acc.z*inv, acc.w*inv);
}

extern "C" void kernel_launch(void* const* d_in, const int* in_sizes, int n_in,
                              void* d_out, int out_size, void* d_ws, size_t ws_size,
                              hipStream_t stream) {
    const float* X  = (const float*)d_in[0];   // [8,2048,512]
    const float* Y  = (const float*)d_in[1];   // [4096,512]
    const float* Z  = (const float*)d_in[2];   // [4096,512]
    const float* Wk = (const float*)d_in[3];   // [512,512]
    const float* Wv = (const float*)d_in[4];   // [256,512]
    float* out = (float*)d_out;

    // workspace layout (~70.6 MB): keyb 4MB + vtb 2MB + Opart NS*16MB +
    // Mpart/Lpart NS*64KB each
    char* ws = (char*)d_ws;
    unsigned short* keyb = (unsigned short*)ws;                    // 4 MB, PACKED
    unsigned short* vtb  = (unsigned short*)(ws + (4u<<20));       // 2 MB, PACKED
    float* Opart = (float*)(ws + (6u<<20));                        // NS x 16 MB
    float* Mpart = (float*)(ws + (6u<<20) + (size_t)NS*NROWS*DVDIM*4);
    float* Lpart = Mpart + (size_t)NS*NROWS;

    // both projections, one launch (epilogues emit packed layouts)
    proj_gemms<<<dim3(64, 8, 2), dim3(256), 0, stream>>>(Y, Z, Wk, Wv, keyb, vtb);
    // fused attention: 2048 blocks (4 SK-splits -> 2x TLP), 2 waves each
    attn_fused<<<dim3(2048), dim3(128), 0, stream>>>(
        X, keyb, vtb, Opart, Mpart, Lpart);
    // merge splits
    combine_splits<<<dim3(NROWS/4), dim3(256), 0, stream>>>(Opart, Mpart, Lpart, out);
}

// Round 14
// 253.883 us; speedup vs baseline: 1.1399x; 1.1399x over previous
//
#include <hip/hip_runtime.h>
#include <hip/hip_bf16.h>

// Problem constants
#define NB    8
#define SQN   2048
#define SKN   4096
#define DDIM  512
#define DVDIM 256
#define NROWS (NB*SQN)      // 16384
#define NS    2             // SK splits (R14: back to 2 — R13's NS=4 added no
                            // resident waves; LDS caps 4 blocks/CU)
#define NJ    ((SKN/64)/NS) // 32 j-iterations per split (64 keys each)

typedef __attribute__((ext_vector_type(8)))  short bf16x8;   // 8 bf16 = 4 VGPRs (MFMA A/B frag)
typedef __attribute__((ext_vector_type(4)))  short bf16x4;
typedef __attribute__((ext_vector_type(4)))  float f32x4;    // 16x16 MFMA C/D frag
typedef __attribute__((ext_vector_type(16))) float f32x16;   // 32x32 MFMA C/D frag

// fp32 -> bf16 round-to-nearest-even, bit pattern as short
__device__ __forceinline__ short f2bf(float f) {
    unsigned u = __float_as_uint(f);
    return (short)((u + 0x7FFFu + ((u >> 16) & 1u)) >> 16);
}

// LDS-only barrier: vm loads (K/V register prefetches) stay in flight.
// sched_barrier fences per rule #18 (no hoisting across the asm wait).
#define BAR_LGKM() do {                                                       \
    asm volatile("s_waitcnt lgkmcnt(0)" ::: "memory");                        \
    __builtin_amdgcn_sched_barrier(0);                                        \
    __builtin_amdgcn_s_barrier();                                             \
    __builtin_amdgcn_sched_barrier(0);                                        \
} while (0)

// ---------------------------------------------------------------------------
// Fused projection GEMMs, one launch. grid = (64, 8, 2).  (unchanged from R8)
// Epilogues write K/V PRE-PACKED in fragment-lane order (16B units;
// lane = hi*32 + l31):
//  K: tile ((J*4+c)*8+tp)*2+kh holds K[J*64+kh*32+l31][c*128+tp*16+hi*8+..7]
//  V: tile (J*8+wv*4+n2)*4+g   holds V^T[wv*128+n2*32+l31][J*64+g*16+hi*8+..7]
// ---------------------------------------------------------------------------
__global__ __launch_bounds__(256, 2) void proj_gemms(
    const float* __restrict__ Y, const float* __restrict__ Z,
    const float* __restrict__ Wk, const float* __restrict__ Wv,
    unsigned short* __restrict__ keyb, unsigned short* __restrict__ vtb)
{
    __shared__ short sA[64*128];   // 16 KB
    __shared__ short sB[64*128];   // 16 KB
    const float *A, *Bm;
    unsigned short* C;
    int m0, n0;
    const bool kpath = (blockIdx.z == 0);
    if (kpath) {
        A = Y; Bm = Wk; C = keyb;
        m0 = blockIdx.x * 64; n0 = blockIdx.y * 64;
    } else {
        int lin = blockIdx.x * 8 + blockIdx.y;
        if (lin >= 256) return;                 // value GEMM needs 256 tiles
        A = Wv; Bm = Z; C = vtb;
        m0 = (lin >> 6) * 64; n0 = (lin & 63) * 64;
    }
    const int tid  = threadIdx.x;
    const int wave = tid >> 6;
    const int lane = tid & 63;
    const int quad = lane >> 4;
    const int l15  = lane & 15;

    f32x4 acc[4];
    #pragma unroll
    for (int n = 0; n < 4; ++n) { acc[n][0]=0.f; acc[n][1]=0.f; acc[n][2]=0.f; acc[n][3]=0.f; }

    float4 ra[8], rb[8];
    #pragma unroll
    for (int it = 0; it < 8; ++it) {            // prefetch kc=0
        int f = it*1024 + tid*4, row = f >> 7, col = f & 127;
        ra[it] = *(const float4*)(A  + (size_t)(m0+row)*DDIM + col);
        rb[it] = *(const float4*)(Bm + (size_t)(n0+row)*DDIM + col);
    }

    for (int kc = 0; kc < DDIM; kc += 128) {
        __syncthreads();                        // LDS free (prev MFMA done)
        #pragma unroll
        for (int it = 0; it < 8; ++it) {
            int f = it*1024 + tid*4;
            bf16x4 a4; a4[0]=f2bf(ra[it].x); a4[1]=f2bf(ra[it].y); a4[2]=f2bf(ra[it].z); a4[3]=f2bf(ra[it].w);
            *(bf16x4*)(sA + f) = a4;
            bf16x4 b4; b4[0]=f2bf(rb[it].x); b4[1]=f2bf(rb[it].y); b4[2]=f2bf(rb[it].z); b4[3]=f2bf(rb[it].w);
            *(bf16x4*)(sB + f) = b4;
        }
        __syncthreads();                        // staged visible
        if (kc + 128 < DDIM) {                  // prefetch kc+1 (in flight under MFMA)
            #pragma unroll
            for (int it = 0; it < 8; ++it) {
                int f = it*1024 + tid*4, row = f >> 7, col = f & 127;
                ra[it] = *(const float4*)(A  + (size_t)(m0+row)*DDIM + kc + 128 + col);
                rb[it] = *(const float4*)(Bm + (size_t)(n0+row)*DDIM + kc + 128 + col);
            }
        }
        #pragma unroll
        for (int t = 0; t < 4; ++t) {
            bf16x8 af = *(const bf16x8*)(sA + (wave*16 + l15)*128 + t*32 + quad*8);
            #pragma unroll
            for (int n = 0; n < 4; ++n) {
                bf16x8 bfr = *(const bf16x8*)(sB + (n*16 + l15)*128 + t*32 + quad*8);
                acc[n] = __builtin_amdgcn_mfma_f32_16x16x32_bf16(af, bfr, acc[n], 0, 0, 0);
            }
        }
    }
    // packed epilogue
    #pragma unroll
    for (int n = 0; n < 4; ++n)
        #pragma unroll
        for (int r = 0; r < 4; ++r) {
            int m  = m0 + wave*16 + quad*4 + r;
            int nn = n0 + n*16 + l15;
            unsigned short v = (unsigned short)f2bf(acc[n][r]);
            size_t off;
            if (kpath) {        // s=m (key row), d=nn
                int J = m >> 6, kh = (m >> 5) & 1, ls = m & 31;
                int c = nn >> 7, tp = (nn >> 4) & 7, hd = (nn >> 3) & 1, d7 = nn & 7;
                off = (size_t)(((J*4 + c)*8 + tp)*2 + kh)*512 + (hd*32 + ls)*8 + d7;
            } else {            // dv=m, key=nn
                int J = nn >> 6, g = (nn >> 4) & 3, hk = (nn >> 3) & 1, k7 = nn & 7;
                int wv = m >> 7, n2 = (m >> 5) & 3, lv = m & 31;
                off = (size_t)((J*8 + wv*4 + n2)*4 + g)*512 + (hk*32 + lv)*8 + k7;
            }
            C[off] = v;
        }
}

// ---------------------------------------------------------------------------
// Fused attention, R14 = R8 (the 152 us best: NS=2, grid 1024, VGPR 100)
// with ONE change: kf ring deepened 3 -> 4 banks (issue kf(h+3) at phase h).
// R13 post-mortem: occupancy is LDS-capped at 4 blocks/CU = 8 waves/CU for
// ANY grid; TLP is locked. Remaining cheap stall: kf lead was 2 phases
// (~256 cyc) vs ~300-600 cyc L2 latency -> ~100-300 cyc exposed per phase.
// Depth-3 gives 384-cyc lead; next-j k0 at h7, k1/k2 pre-bar2 (>1000 cyc);
// V windows at h5/h6. Cost +16 arch VGPR (~116 <= 128, occupancy intact).
// Ring WAR: bank h&3 read at phase h, rewritten at h+1 for h+4 (one phase
// after last read) — same pattern as R8's proven 3-bank ring.
// Everything else byte-identical to R8: packed coalesced K/V global->reg,
// Q in LDS, wk-pair key split w/ 2 lgkm-only exchanges/j, T13 defer-max
// log2 softmax, cvt_pk+permlane P->A-frags, XCD-split swizzle.
// grid = 1024 (4 blocks/CU), block = 128 (one wk pair).
// ---------------------------------------------------------------------------
__global__ __launch_bounds__(128, 2) void attn_fused(
    const float* __restrict__ X,            // [16384][512] fp32
    const unsigned short* __restrict__ Kb,  // key bf16, PACKED (4 MB)
    const unsigned short* __restrict__ Vt,  // V^T bf16, PACKED (2 MB)
    float* __restrict__ Opart,              // [NS][16384][256]
    float* __restrict__ Mpart,              // [NS][16384] (log2 domain)
    float* __restrict__ Lpart)              // [NS][16384]
{
    // 0     : sQ 32KB [t2=32][lane]x16B  (Q B-frag tile t2: elem e =
    //         X[q0+l31][t2*16 + hi*8 + e]*scale)
    // 32768 : sPex 4KB [wk*2+ks][lane]x16B P A-frags
    // 36864 : sSt 512B [wk*2+slot][32] floats
    __shared__ __align__(16) char smem[37376];
    char* sQ   = smem;
    char* sPex = smem + 32768;
    float* sSt = (float*)(smem + 36864);

    const int tid  = threadIdx.x;
    const int wk   = tid >> 6;      // 0..1: key-half for QK / dv-half for PV
    const int lane = tid & 63;
    const int l31  = lane & 31;
    const int hi   = lane >> 5;

    // XCD-split swizzle: bid&7 = XCD; XCD 0-3 -> split 0, 4-7 -> split 1.
    const int bid   = blockIdx.x;          // 0..1023
    const int xcd   = bid & 7;
    const int slot  = bid >> 3;            // 0..127
    const int split = xcd >> 2;
    const int q0    = ((xcd & 3)*128 + slot) * 32;
    // 1/sqrt(512) * log2(e): softmax runs in log2 domain (exp2)
    const float scale = 0.04419417382415922f * 1.4426950408889634f;

    // ---- prologue: stage this block's 32 Q frag-tiles to LDS (wk splits) ----
    {
        const float* xrow = X + (size_t)(q0 + l31)*DDIM + hi*8;
        #pragma unroll
        for (int i = 0; i < 16; ++i) {
            const int t2 = wk*16 + i;
            float4 a = *(const float4*)(xrow + t2*16);
            float4 b = *(const float4*)(xrow + t2*16 + 4);
            bf16x8 q;
            q[0]=f2bf(a.x*scale); q[1]=f2bf(a.y*scale); q[2]=f2bf(a.z*scale); q[3]=f2bf(a.w*scale);
            q[4]=f2bf(b.x*scale); q[5]=f2bf(b.y*scale); q[6]=f2bf(b.z*scale); q[7]=f2bf(b.w*scale);
            *(bf16x8*)(sQ + t2*1024 + lane*16) = q;
        }
    }

    // O acc: D[row=q][col=dv], wave's dv-half = wk*128 + n*32 + l31.
    f32x16 o[4];
    #pragma unroll
    for (int n = 0; n < 4; ++n)
        #pragma unroll
        for (int r = 0; r < 16; ++r) o[n][r] = 0.f;
    float m_r = -1e30f, l_r = 0.f;       // shared across wk pair

    // packed base pointers (this wave's key-half / dv-half, lane folded in)
    const int Jg0 = split * NJ;
    const char* kp = (const char*)Kb + (size_t)Jg0*65536 + wk*1024 + lane*16;
    const char* vp = (const char*)Vt + (size_t)Jg0*32768 + wk*16384 + lane*16;
    // K frag (h,t): kp + (h>>1)*16384 + (((h&1)*4+t)*2)*1024
    // V frag (n,g): vp + n*4096 + g*1024
    #define KOFF(h_, t_) ((size_t)((h_)>>1)*16384 + (size_t)((((h_)&1)*4 + (t_))*2)*1024)

    bf16x8 kf[4][4];                    // depth-3 ring, 4 banks (64 VGPR)
    bf16x8 vf[2][4];                    // PV double buffer (32 VGPR)

    BAR_LGKM();                         // Q visible to the pair

    // load K half-chunk h_ (+joff_ bytes) into bank b_
    #define LD_KF(b_, h_, joff_)                                              \
        do { _Pragma("unroll")                                                \
             for (int t_ = 0; t_ < 4; ++t_)                                   \
                 kf[b_][t_] = *(const bf16x8*)(kp + (joff_) + KOFF(h_, t_));  \
        } while (0)

    // prologue loads: j=0 half-chunks 0,1,2 -> banks 0,1,2
    LD_KF(0, 0, 0); LD_KF(1, 1, 0); LD_KF(2, 2, 0);

    const char* qb = sQ + lane*16;

    for (int j = 0; j < NJ; ++j) {
        f32x16 s;                       // P^T acc: D[row=key][col=q]
        #pragma unroll
        for (int r = 0; r < 16; ++r) s[r] = 0.f;

        // ---- QK: 8 phases; issue kf(h+3) at phase h (depth-3, 384-cyc
        //      lead); V g0/g1 at h5/h6; next-j k0 at h7 ----
        #pragma unroll
        for (int h = 0; h < 8; ++h) {
            if (h < 5) {
                LD_KF((h + 3) & 3, h + 3, 0);
            } else if (h == 5 || h == 6) {
                const int g = h - 5;    // V windows g=0,1
                #pragma unroll
                for (int n = 0; n < 4; ++n)
                    vf[g][n] = *(const bf16x8*)(vp + n*4096 + g*1024);
            } else {
                if (j + 1 < NJ) LD_KF(0, 0, 65536);   // next-j k0 -> bank0
            }
            __builtin_amdgcn_s_setprio(1);
            #pragma unroll
            for (int t = 0; t < 4; ++t) {
                bf16x8 qv = *(const bf16x8*)(qb + (h*4 + t)*1024);
                s = __builtin_amdgcn_mfma_f32_32x32x16_bf16(
                        kf[h & 3][t], qv, s, 0, 0, 0);
            }
            __builtin_amdgcn_s_setprio(0);
        }

        // ---- softmax (log2 domain), in-lane; joint max across wk pair ----
        float tmax = fmaxf(fmaxf(fmaxf(s[0],s[1]),fmaxf(s[2],s[3])),
                           fmaxf(fmaxf(s[4],s[5]),fmaxf(s[6],s[7])));
        tmax = fmaxf(tmax, fmaxf(fmaxf(fmaxf(s[8],s[9]),fmaxf(s[10],s[11])),
                                 fmaxf(fmaxf(s[12],s[13]),fmaxf(s[14],s[15]))));
        tmax = fmaxf(tmax, __shfl_xor(tmax, 32));
        if (lane < 32) sSt[(wk*2 + 0)*32 + lane] = tmax;
        BAR_LGKM();                                             // exchange 1
        float tmax_o = sSt[((wk^1)*2 + 0)*32 + l31];
        const float tj   = fmaxf(tmax, tmax_o);
        // T13 defer-max: only move the reference when it grew by >8 (p <= 2^8)
        const bool  upd  = tj > m_r + 8.0f;
        const float mn   = upd ? tj : m_r;
        float tsum = 0.f;
        #pragma unroll
        for (int r = 0; r < 16; ++r) { float pv = exp2f(s[r] - mn); s[r] = pv; tsum += pv; }
        tsum += __shfl_xor(tsum, 32);

        // P -> PV A-frags in-register (cvt_pk + permlane32_swap, proven R1-R13)
        bf16x8 pf[2];
        #pragma unroll
        for (int ks = 0; ks < 2; ++ks) {
            int wA, wB, wC, wD;
            asm("v_cvt_pk_bf16_f32 %0, %1, %2" : "=v"(wA) : "v"(s[8*ks+0]), "v"(s[8*ks+1]));
            asm("v_cvt_pk_bf16_f32 %0, %1, %2" : "=v"(wB) : "v"(s[8*ks+2]), "v"(s[8*ks+3]));
            asm("v_cvt_pk_bf16_f32 %0, %1, %2" : "=v"(wC) : "v"(s[8*ks+4]), "v"(s[8*ks+5]));
            asm("v_cvt_pk_bf16_f32 %0, %1, %2" : "=v"(wD) : "v"(s[8*ks+6]), "v"(s[8*ks+7]));
            asm("v_permlane32_swap_b32 %0, %1" : "+v"(wA), "+v"(wC));
            asm("v_permlane32_swap_b32 %0, %1" : "+v"(wB), "+v"(wD));
            union { int w[4]; bf16x8 v; } u;
            u.w[0] = wA; u.w[1] = wB; u.w[2] = wC; u.w[3] = wD;
            pf[ks] = u.v;
        }
        *(bf16x8*)(sPex + (wk*2 + 0)*1024 + lane*16) = pf[0];
        *(bf16x8*)(sPex + (wk*2 + 1)*1024 + lane*16) = pf[1];
        if (lane < 32) sSt[(wk*2 + 1)*32 + lane] = tsum;

        // issue next-j K half-chunks 1,2 (k0 went at h7; in flight across
        // exchange+PV, consumed at next-j phases 1,2)
        if (j + 1 < NJ) {
            LD_KF(1, 1, 65536);
            LD_KF(2, 2, 65536);
            kp += 65536;
        }
        BAR_LGKM();                                             // exchange 2
        float tsum_o = sSt[((wk^1)*2 + 1)*32 + l31];
        float alpha  = upd ? exp2f(m_r - mn) : 1.0f;
        l_r = l_r*alpha + (tsum + tsum_o);
        m_r = mn;
        if (__any(upd)) {               // rescale O (alpha indexed by q-row)
            #pragma unroll
            for (int r = 0; r < 16; ++r) {
                int row = (r&3) + 8*(r>>2) + 4*hi;
                float ar = __shfl(alpha, row);
                #pragma unroll
                for (int n = 0; n < 4; ++n) o[n][r] *= ar;
            }
        }

        // ---- PV: O[dv-half wk] += P(all 64 keys) * V^T; issue V(g+2)
        //      after MFMAs of g (buffer free, drains under next phase) ----
        const char* pb = sPex + lane*16;
        #pragma unroll
        for (int g = 0; g < 4; ++g) {
            bf16x8 pa = ((g >> 1) == wk) ? pf[g & 1]
                        : *(const bf16x8*)(pb + g*1024);
            __builtin_amdgcn_s_setprio(1);
            #pragma unroll
            for (int n = 0; n < 4; ++n)
                o[n] = __builtin_amdgcn_mfma_f32_32x32x16_bf16(
                        pa, vf[g & 1][n], o[n], 0, 0, 0);
            __builtin_amdgcn_s_setprio(0);
            if (g < 2) {
                #pragma unroll
                for (int n = 0; n < 4; ++n)
                    vf[g][n] = *(const bf16x8*)(vp + n*4096 + (g + 2)*1024);
            }
        }
        vp += 32768;
    }
    #undef LD_KF
    #undef KOFF

    // ---- epilogue: shared (m,l) across wk; disjoint dv halves -> no merge ----
    const size_t base = (size_t)split * NROWS;
    if (wk == 0 && lane < 32) {
        Mpart[base + q0 + lane] = m_r;      // log2 domain
        Lpart[base + q0 + lane] = l_r;
    }
    #pragma unroll
    for (int r = 0; r < 16; ++r) {
        int row = (r&3) + 8*(r>>2) + 4*hi;
        float* orow = Opart + (base + q0 + row) * (size_t)DVDIM + wk*128;
        #pragma unroll
        for (int n = 0; n < 4; ++n)
            orow[n*32 + l31] = o[n][r];
    }
}

// ---------------------------------------------------------------------------
// Combine NS split partials: out = sum_s(Os*ws) / sum_s(ls*ws), ws=2^(ms-M)
// (Mpart is log2-domain). grid = NROWS/4, block = 256. Coalesced.
// ---------------------------------------------------------------------------
__global__ void combine_splits(
    const float* __restrict__ Opart, const float* __restrict__ Mpart,
    const float* __restrict__ Lpart, float* __restrict__ out)
{
    const int row = blockIdx.x * 4 + (threadIdx.x >> 6);
    const int dv4 = (threadIdx.x & 63) * 4;
    float M = -1e30f;
    #pragma unroll
    for (int s = 0; s < NS; ++s) M = fmaxf(M, Mpart[(size_t)s*NROWS + row]);
    float denom = 0.f;
    float4 acc = make_float4(0.f, 0.f, 0.f, 0.f);
    #pragma unroll
    for (int s = 0; s < NS; ++s) {
        float w = exp2f(Mpart[(size_t)s*NROWS + row] - M);
        denom += Lpart[(size_t)s*NROWS + row] * w;
        float4 ov = *(const float4*)(Opart + ((size_t)s*NROWS + row)*DVDIM + dv4);
        acc.x += ov.x*w; acc.y += ov.y*w; acc.z += ov.z*w; acc.w += ov.w*w;
    }
    float inv = 1.0f / denom;
    *(float4*)(out + (size_t)row*DVDIM + dv4)
        = make_float4(acc.x*inv, acc.y*inv, acc.z*inv, acc.w*inv);
}

extern "C" void kernel_launch(void* const* d_in, const int* in_sizes, int n_in,
                              void* d_out, int out_size, void* d_ws, size_t ws_size,
                              hipStream_t stream) {
    const float* X  = (const float*)d_in[0];   // [8,2048,512]
    const float* Y  = (const float*)d_in[1];   // [4096,512]
    const float* Z  = (const float*)d_in[2];   // [4096,512]
    const float* Wk = (const float*)d_in[3];   // [512,512]
    const float* Wv = (const float*)d_in[4];   // [256,512]
    float* out = (float*)d_out;

    // workspace layout (~38.3 MB)
    char* ws = (char*)d_ws;
    unsigned short* keyb = (unsigned short*)ws;                    // 4 MB, PACKED
    unsigned short* vtb  = (unsigned short*)(ws + (4u<<20));       // 2 MB, PACKED
    float* Opart = (float*)(ws + (6u<<20));                        // NS x 16 MB
    float* Mpart = (float*)(ws + (6u<<20) + (size_t)NS*NROWS*DVDIM*4);
    float* Lpart = Mpart + (size_t)NS*NROWS;

    // both projections, one launch (epilogues emit packed layouts)
    proj_gemms<<<dim3(64, 8, 2), dim3(256), 0, stream>>>(Y, Z, Wk, Wv, keyb, vtb);
    // fused attention: 1024 blocks (4/CU), depth-3 kf ring, packed K/V to regs
    attn_fused<<<dim3(1024), dim3(128), 0, stream>>>(
        X, keyb, vtb, Opart, Mpart, Lpart);
    // merge splits
    combine_splits<<<dim3(NROWS/4), dim3(256), 0, stream>>>(Opart, Mpart, Lpart, out);
}